// Round 6
// baseline (1870.408 us; speedup 1.0000x reference)
//
#include <hip/hip_runtime.h>
#include <stdint.h>

#define NN 131072
#define NE 2097152
#define NG 1024

typedef float f32x4 __attribute__((ext_vector_type(4)));
typedef short bf16x8 __attribute__((ext_vector_type(8)));

// monotone float<->uint encoding: f1 < f2  <=>  enc(f1) < enc(f2) (unsigned).
__device__ __forceinline__ unsigned enc_f32(float f) {
  unsigned b = __float_as_uint(f);
  return (b & 0x80000000u) ? ~b : (b | 0x80000000u);
}
__device__ __forceinline__ float dec_pos(unsigned u) {
  return __uint_as_float(u & 0x7fffffffu);
}
// pack the high16 (truncated bf16) of two fp32 into one dword: [u1.hi | u0.hi]
__device__ __forceinline__ unsigned pack_hi(unsigned u0, unsigned u1) {
  return __builtin_amdgcn_perm(u1, u0, 0x07060302u);
}

// ---------------- init ----------------
__global__ void init_ws(uint4* __restrict__ h1, uint4* __restrict__ h2,
                        int* __restrict__ counts, int* __restrict__ fill,
                        int* __restrict__ bcnt) {
  const int HN4 = NN * 64 / 4;
  uint4 v = make_uint4(0x80000000u, 0x80000000u, 0x80000000u, 0x80000000u);
  int stride = gridDim.x * blockDim.x;
  for (int t = blockIdx.x * blockDim.x + threadIdx.x; t < HN4; t += stride) {
    h1[t] = v;
    h2[t] = v;
  }
  for (int t = blockIdx.x * blockDim.x + threadIdx.x; t < NN; t += stride) {
    counts[t] = 0;
    fill[t] = 0;
  }
  for (int t = blockIdx.x * blockDim.x + threadIdx.x; t < NG; t += stride)
    bcnt[t] = 0;
}

// ---------------- CSR build ----------------
__global__ __launch_bounds__(256) void count_all(const int* __restrict__ dst,
                                                 const int* __restrict__ batch,
                                                 int* __restrict__ counts,
                                                 int* __restrict__ bcnt) {
  int e = blockIdx.x * 256 + threadIdx.x;
  atomicAdd(&counts[dst[e]], 1);
  if (e < NN) atomicAdd(&bcnt[batch[e]], 1);
}

__global__ __launch_bounds__(256) void scanA(const int* __restrict__ counts,
                                             int* __restrict__ rp,
                                             int* __restrict__ bsum) {
  __shared__ int sm[256];
  int t = threadIdx.x;
  int g = blockIdx.x * 256 + t;
  int v = counts[g];
  sm[t] = v;
  __syncthreads();
  for (int off = 1; off < 256; off <<= 1) {
    int a = (t >= off) ? sm[t - off] : 0;
    __syncthreads();
    sm[t] += a;
    __syncthreads();
  }
  rp[g] = sm[t] - v;
  if (t == 255) bsum[blockIdx.x] = sm[255];
}

__global__ __launch_bounds__(512) void scanB(int* __restrict__ bsum) {
  __shared__ int sm[512];
  int t = threadIdx.x;
  int v = bsum[t];
  sm[t] = v;
  __syncthreads();
  for (int off = 1; off < 512; off <<= 1) {
    int a = (t >= off) ? sm[t - off] : 0;
    __syncthreads();
    sm[t] += a;
    __syncthreads();
  }
  bsum[t] = sm[t] - v;
}

__global__ __launch_bounds__(256) void scanC(int* __restrict__ rp,
                                             const int* __restrict__ bsum) {
  int g = blockIdx.x * 256 + threadIdx.x;
  rp[g] += bsum[blockIdx.x];
  if (g == 0) rp[NN] = NE;
}

__global__ __launch_bounds__(1024) void scan_batch(const int* __restrict__ bcnt,
                                                   int* __restrict__ bp) {
  __shared__ int sm[1024];
  int t = threadIdx.x;
  int v = bcnt[t];
  sm[t] = v;
  __syncthreads();
  for (int off = 1; off < 1024; off <<= 1) {
    int a = (t >= off) ? sm[t - off] : 0;
    __syncthreads();
    sm[t] += a;
    __syncthreads();
  }
  bp[t] = sm[t] - v;
  if (t == 1023) bp[NG] = NN;
}

__global__ __launch_bounds__(256) void scatter(
    const int* __restrict__ src, const int* __restrict__ dst,
    const float* __restrict__ ea, const int* __restrict__ rp,
    int* __restrict__ fill, int* __restrict__ eperm, int* __restrict__ sp,
    int* __restrict__ dst_p, float* __restrict__ ea_p, int use_eap) {
  int e = blockIdx.x * 256 + threadIdx.x;
  int d = dst[e];
  int p = rp[d] + atomicAdd(&fill[d], 1);
  sp[p] = src[e];
  dst_p[p] = d;
  if (use_eap) {
    const float2* s2 = (const float2*)(ea + (size_t)e * 6);
    float2 a = s2[0], b = s2[1], c = s2[2];
    float2* d2 = (float2*)(ea_p + (size_t)p * 6);
    d2[0] = a; d2[1] = b; d2[2] = c;
  } else {
    eperm[p] = e;
  }
}

// ---------------- W2 -> bf16 hi/lo B-fragment pre-pack ----------------
// layout per conv: [dt(2: hi,lo)][kc(2)][nt(4)][lane(64)][4 dwords]
// B-frag for mfma_f32_16x16x32_bf16: lane l holds B[k][n] with n = nt*16+(l&15),
// k = kc*32 + (l>>4)*8 + j (j=0..7, 2 bf16/dword, low16 = even j).
__global__ __launch_bounds__(1024) void prep_w2(const float* __restrict__ w2a,
                                                const float* __restrict__ w2b,
                                                unsigned* __restrict__ w2f) {
  int tid = threadIdx.x;
  const float* w2 = blockIdx.x ? w2b : w2a;
  unsigned* outp = w2f + blockIdx.x * 4096;
  int dt = tid >> 9, kc = (tid >> 8) & 1, nt = (tid >> 6) & 3, lane = tid & 63;
  int kbase = kc * 32 + (lane >> 4) * 8;
  int n = nt * 16 + (lane & 15);
  unsigned dwords[4];
#pragma unroll
  for (int i = 0; i < 4; i++) {
    float w0 = w2[(kbase + 2 * i) * 64 + n];
    float w1 = w2[(kbase + 2 * i + 1) * 64 + n];
    unsigned u0 = __float_as_uint(w0), u1 = __float_as_uint(w1);
    if (dt == 0) {
      dwords[i] = pack_hi(u0, u1);
    } else {
      float l0 = w0 - __uint_as_float(u0 & 0xffff0000u);
      float l1 = w1 - __uint_as_float(u1 & 0xffff0000u);
      dwords[i] = pack_hi(__float_as_uint(l0), __float_as_uint(l1));
    }
  }
  *(uint4*)(outp + ((dt * 2 + kc) * 4 + nt) * 256 + lane * 4) =
      make_uint4(dwords[0], dwords[1], dwords[2], dwords[3]);
}

// ---------------- node-level GEMMs: P = H@Wd + b1, Q = H@Ws ----------------
__global__ __launch_bounds__(256, 4) void nodePQ1(
    const float* __restrict__ x, const float* __restrict__ w1,
    const float* __restrict__ b1, float* __restrict__ P, float* __restrict__ Q) {
  int half = blockIdx.x >> 9;
  int n = (blockIdx.x & 511) * 256 + threadIdx.x;
  const float* w = w1 + half * 16 * 64;
  float acc[64];
#pragma unroll
  for (int j = 0; j < 64; j++) acc[j] = half ? 0.0f : b1[j];
  const float4* x4 = (const float4*)(x + (size_t)n * 16);
#pragma unroll
  for (int kk = 0; kk < 4; kk++) {
    float4 v = x4[kk];
    const float* wr = w + (kk * 4) * 64;
#pragma unroll
    for (int j = 0; j < 64; j++) acc[j] = fmaf(v.x, wr[j], acc[j]);
#pragma unroll
    for (int j = 0; j < 64; j++) acc[j] = fmaf(v.y, wr[64 + j], acc[j]);
#pragma unroll
    for (int j = 0; j < 64; j++) acc[j] = fmaf(v.z, wr[128 + j], acc[j]);
#pragma unroll
    for (int j = 0; j < 64; j++) acc[j] = fmaf(v.w, wr[192 + j], acc[j]);
  }
  float4* o = (float4*)((half ? Q : P) + (size_t)n * 64);
#pragma unroll
  for (int j = 0; j < 16; j++)
    o[j] = make_float4(acc[4 * j], acc[4 * j + 1], acc[4 * j + 2], acc[4 * j + 3]);
}

__global__ __launch_bounds__(256, 4) void nodePQ2(
    const unsigned* __restrict__ h1, const float* __restrict__ w1,
    const float* __restrict__ b1, float* __restrict__ P, float* __restrict__ Q) {
  int half = blockIdx.x >> 9;
  int n = (blockIdx.x & 511) * 256 + threadIdx.x;
  const float* w = w1 + half * 64 * 64;
  float acc[64];
#pragma unroll
  for (int j = 0; j < 64; j++) acc[j] = half ? 0.0f : b1[j];
  const uint4* h4 = (const uint4*)(h1 + (size_t)n * 64);
#pragma unroll 4
  for (int kk = 0; kk < 16; kk++) {
    uint4 u = h4[kk];
    float v0 = dec_pos(u.x), v1 = dec_pos(u.y), v2 = dec_pos(u.z), v3 = dec_pos(u.w);
    const float* wr = w + (kk * 4) * 64;
#pragma unroll
    for (int j = 0; j < 64; j++) acc[j] = fmaf(v0, wr[j], acc[j]);
#pragma unroll
    for (int j = 0; j < 64; j++) acc[j] = fmaf(v1, wr[64 + j], acc[j]);
#pragma unroll
    for (int j = 0; j < 64; j++) acc[j] = fmaf(v2, wr[128 + j], acc[j]);
#pragma unroll
    for (int j = 0; j < 64; j++) acc[j] = fmaf(v3, wr[192 + j], acc[j]);
  }
  float4* o = (float4*)((half ? Q : P) + (size_t)n * 64);
#pragma unroll
  for (int j = 0; j < 16; j++)
    o[j] = make_float4(acc[4 * j], acc[4 * j + 1], acc[4 * j + 2], acc[4 * j + 3]);
}

// ---------------- edge kernel: MFMA layer-2, wave = 64 CSR slots ----------------
// h(64 edges x 64 hidden) built on VALU in K-chunks of 32, split to bf16 hi/lo
// in a per-wave LDS tile; out = h @ W2 via mfma 16x16x32 with 3-term split
// (hi*hi + hi*lo + lo*hi); bias folded into acc init; epilogue = C dump to
// [ch][edge] LDS + serial uniform segmented max (round-5 proven logic).
template <bool EAP>
__global__ __launch_bounds__(256, 4) void edge_mfma(
    const float* __restrict__ P, const float* __restrict__ Q,
    const float* __restrict__ ea_p, const float* __restrict__ ea,
    const int* __restrict__ eperm, const int* __restrict__ sp,
    const int* __restrict__ dst_p, const int* __restrict__ rp,
    const float* __restrict__ w1c, const unsigned* __restrict__ w2f,
    const float* __restrict__ b2, unsigned* __restrict__ hout) {
  __shared__ __align__(16) unsigned lds[4][2176];  // per-wave 8.5 KB tile
  __shared__ int dar[4][64];

  int tid = threadIdx.x, wv = tid >> 6, lane = tid & 63;
  int lc = lane & 15, lg = lane >> 4;
  int g = blockIdx.x * 256 + tid;  // CSR slot; lane = slot within wave-tile
  int d = dst_p[g], s = sp[g];
  int seg_lo = rp[d], seg_hi = rp[d + 1];
  int wavebase = g - lane;
  bool whole = (seg_lo >= wavebase) && (seg_hi <= wavebase + 64);
  dar[wv][lane] = d | (whole ? (int)0x80000000 : 0);

  float2 ev[3];
  if (EAP) {
    const float2* q = (const float2*)(ea_p + (size_t)g * 6);
    ev[0] = q[0]; ev[1] = q[1]; ev[2] = q[2];
  } else {
    int e = eperm[g];
    const float2* q = (const float2*)(ea + (size_t)e * 6);
    ev[0] = q[0]; ev[1] = q[1]; ev[2] = q[2];
  }

  // acc init = bias (C/D layout: lane holds ch = nt*16+lc, rows = edges)
  f32x4 acc[4][4];
#pragma unroll
  for (int nt = 0; nt < 4; nt++) {
    float bv = b2[nt * 16 + lc];
#pragma unroll
    for (int mt = 0; mt < 4; mt++) acc[mt][nt] = (f32x4){bv, bv, bv, bv};
  }

  unsigned* hi_t = lds[wv];         // 64 rows x 16 dwords, block-XOR swizzled
  unsigned* lo_t = lds[wv] + 1024;
  int kw = (lane >> 1) & 3;  // write swizzle key (row = lane)
  int ka = (lc >> 1) & 3;    // A-frag read swizzle key (row = mt*16+lc)

#pragma unroll 1
  for (int kc = 0; kc < 2; ++kc) {
    float hj[32];
    {
      const float4* Pd = (const float4*)(P + (size_t)d * 64 + kc * 32);
      const float4* Qs = (const float4*)(Q + (size_t)s * 64 + kc * 32);
#pragma unroll
      for (int i = 0; i < 8; i++) {
        float4 a = Pd[i];
        float4 b = Qs[i];
        hj[4 * i] = a.x + b.x;
        hj[4 * i + 1] = a.y + b.y;
        hj[4 * i + 2] = a.z + b.z;
        hj[4 * i + 3] = a.w + b.w;
      }
#pragma unroll
      for (int t = 0; t < 3; t++) {
        const float* wr = w1c + (2 * t) * 64 + kc * 32;
#pragma unroll
        for (int j = 0; j < 32; j++) hj[j] = fmaf(ev[t].x, wr[j], hj[j]);
#pragma unroll
        for (int j = 0; j < 32; j++) hj[j] = fmaf(ev[t].y, wr[64 + j], hj[j]);
      }
#pragma unroll
      for (int j = 0; j < 32; j++) hj[j] = fmaxf(hj[j], 0.0f);
    }

    if (kc) asm volatile("s_waitcnt lgkmcnt(0)" ::: "memory");  // WAR vs kc=0 reads
#pragma unroll
    for (int q = 0; q < 4; q++) {  // 4-dword blocks, truncation hi/lo split
      unsigned hd[4], ld_[4];
#pragma unroll
      for (int i = 0; i < 4; i++) {
        float h0 = hj[q * 8 + 2 * i], h1 = hj[q * 8 + 2 * i + 1];
        unsigned u0 = __float_as_uint(h0), u1 = __float_as_uint(h1);
        hd[i] = pack_hi(u0, u1);
        float l0 = h0 - __uint_as_float(u0 & 0xffff0000u);
        float l1 = h1 - __uint_as_float(u1 & 0xffff0000u);
        ld_[i] = pack_hi(__float_as_uint(l0), __float_as_uint(l1));
      }
      int a = lane * 16 + 4 * (q ^ kw);
      *(uint4*)(hi_t + a) = make_uint4(hd[0], hd[1], hd[2], hd[3]);
      *(uint4*)(lo_t + a) = make_uint4(ld_[0], ld_[1], ld_[2], ld_[3]);
    }
    asm volatile("s_waitcnt lgkmcnt(0)" ::: "memory");  // writes visible to frag reads

    bf16x8 ah[4], al[4];
#pragma unroll
    for (int mt = 0; mt < 4; mt++) {
      int a = (mt * 16 + lc) * 16 + 4 * (lg ^ ka);
      ah[mt] = *(bf16x8*)(hi_t + a);
      al[mt] = *(bf16x8*)(lo_t + a);
    }
#pragma unroll
    for (int nt = 0; nt < 4; nt++) {
      bf16x8 bh = *(const bf16x8*)(w2f + ((0 + kc) * 4 + nt) * 256 + lane * 4);
      bf16x8 bl = *(const bf16x8*)(w2f + ((2 + kc) * 4 + nt) * 256 + lane * 4);
#pragma unroll
      for (int mt = 0; mt < 4; mt++) {
        acc[mt][nt] = __builtin_amdgcn_mfma_f32_16x16x32_bf16(ah[mt], bh, acc[mt][nt], 0, 0, 0);
        acc[mt][nt] = __builtin_amdgcn_mfma_f32_16x16x32_bf16(ah[mt], bl, acc[mt][nt], 0, 0, 0);
        acc[mt][nt] = __builtin_amdgcn_mfma_f32_16x16x32_bf16(al[mt], bh, acc[mt][nt], 0, 0, 0);
      }
    }
  }

  // ---- epilogue: per 32-ch half, dump C as [ch][edge] (pad 68, XOR-swizzled
  // edge index for conflict-free serial reads), then uniform segmented max ----
  float* ct = (float*)lds[wv];  // 32 x 68 = 2176 dwords, aliases h tiles
  int kx = 4 * ((lane >> 3) & 3);  // scan-read XOR key (lane = channel row)
#pragma unroll 1
  for (int half = 0; half < 2; ++half) {
    asm volatile("s_waitcnt lgkmcnt(0)" ::: "memory");  // prior reads done
#pragma unroll
    for (int nt2 = 0; nt2 < 2; nt2++) {
      int nt = half * 2 + nt2;
      int chl = nt2 * 16 + lc;
      int kc2 = 4 * ((chl >> 3) & 3);
#pragma unroll
      for (int mt = 0; mt < 4; mt++) {
        int cb = (mt * 16 + 4 * lg) ^ kc2;
        *(f32x4*)(ct + chl * 68 + cb) = acc[mt][nt];
      }
    }
    asm volatile("s_waitcnt lgkmcnt(0)" ::: "memory");  // C visible to scan
    if (lane < 32) {
      float mx = 0.0f;
      int cur = dar[wv][0];
      int base = lane * 68;
#pragma unroll 8
      for (int e = 0; e < 64; ++e) {
        float v = ct[base + (e ^ kx)];
        mx = fmaxf(mx, v);
        int nxt = (e < 63) ? dar[wv][e + 1] : 0x7fffffff;
        if (cur != nxt) {  // uniform: segment boundary -> flush
          unsigned* addr = hout + (size_t)(cur & 0x7fffffff) * 64 + half * 32 + lane;
          unsigned encv = enc_f32(mx);
          if (cur < 0) *addr = encv;   // whole-in-wave: plain store
          else atomicMax(addr, encv);  // crosses wave boundary
          mx = 0.0f;
        }
        cur = nxt;
      }
    }
  }
}

// ---------------- fused mean-pool + readout: 4-wave block per graph ----------------
__global__ __launch_bounds__(256) void readout(
    const unsigned* __restrict__ h2, const int* __restrict__ bp,
    const float* __restrict__ wr1, const float* __restrict__ br1,
    const float* __restrict__ wr2, const float* __restrict__ br2,
    float* __restrict__ out) {
  int g = blockIdx.x;
  int tid = threadIdx.x;
  int wv = tid >> 6, lane = tid & 63;
  int lo = bp[g], hi = bp[g + 1];
  float s = 0.0f;
  for (int n = lo + wv; n < hi; n += 4) s += dec_pos(h2[(size_t)n * 64 + lane]);
  __shared__ float part[4][64];
  __shared__ float p[64], t[64];
  part[wv][lane] = s;
  __syncthreads();
  if (tid < 64) {
    float c = fmaxf((float)(hi - lo), 1.0f);
    p[tid] = (part[0][tid] + part[1][tid] + part[2][tid] + part[3][tid]) / c;
  }
  __syncthreads();
  if (tid < 64) {
    float a = br1[tid];
#pragma unroll 8
    for (int k = 0; k < 64; k++) a = fmaf(p[k], wr1[k * 64 + tid], a);
    t[tid] = fmaxf(a, 0.0f);
  }
  __syncthreads();
  if (tid < 64) {
    float z0 = br2[tid], z1 = br2[64 + tid];
#pragma unroll 8
    for (int k = 0; k < 64; k++) {
      float tk = t[k];
      z0 = fmaf(tk, wr2[k * 128 + tid], z0);
      z1 = fmaf(tk, wr2[k * 128 + 64 + tid], z1);
    }
    out[(size_t)g * 128 + tid] = z0;
    out[(size_t)g * 128 + 64 + tid] = z1;
  }
}

// ---------------- launch ----------------
extern "C" void kernel_launch(void* const* d_in, const int* in_sizes, int n_in,
                              void* d_out, int out_size, void* d_ws, size_t ws_size,
                              hipStream_t stream) {
  const float* x     = (const float*)d_in[0];
  const float* ea    = (const float*)d_in[1];
  const int*   ei    = (const int*)d_in[2];
  const int*   batch = (const int*)d_in[3];
  const float* w11 = (const float*)d_in[4];
  const float* b11 = (const float*)d_in[5];
  const float* w12 = (const float*)d_in[6];
  const float* b12 = (const float*)d_in[7];
  const float* w21 = (const float*)d_in[8];
  const float* b21 = (const float*)d_in[9];
  const float* w22 = (const float*)d_in[10];
  const float* b22 = (const float*)d_in[11];
  const float* wr1 = (const float*)d_in[12];
  const float* br1 = (const float*)d_in[13];
  const float* wr2 = (const float*)d_in[14];
  const float* br2 = (const float*)d_in[15];
  float* out = (float*)d_out;

  const int* src = ei;
  const int* dst = ei + NE;

  char* ws = (char*)d_ws;
  size_t off = 0;
  auto alloc = [&](size_t bytes) {
    char* p = ws + off;
    off = (off + bytes + 255) & ~(size_t)255;
    return p;
  };
  unsigned* h1   = (unsigned*)alloc((size_t)NN * 64 * 4);
  unsigned* h2   = (unsigned*)alloc((size_t)NN * 64 * 4);
  float*    Pbuf = (float*)alloc((size_t)NN * 64 * 4);
  float*    Qbuf = (float*)alloc((size_t)NN * 64 * 4);
  int*   sp    = (int*)alloc((size_t)NE * 4);
  int*   eperm = (int*)alloc((size_t)NE * 4);
  int*   dst_p = (int*)alloc((size_t)NE * 4);
  int*   rp    = (int*)alloc((size_t)(NN + 1) * 4);
  int*   counts= (int*)alloc((size_t)NN * 4);
  int*   fill  = (int*)alloc((size_t)NN * 4);
  int*   bcnt  = (int*)alloc((size_t)NG * 4);
  int*   bp    = (int*)alloc((size_t)(NG + 1) * 4);
  int*   bsum  = (int*)alloc(512 * 4);
  unsigned* w2f = (unsigned*)alloc(2 * 4096 * 4);  // packed bf16 B-frags, 32 KB
  float* ea_p  = (float*)alloc((size_t)NE * 6 * 4);
  int use_eap = (off <= ws_size) ? 1 : 0;

  init_ws<<<1024, 256, 0, stream>>>((uint4*)h1, (uint4*)h2, counts, fill, bcnt);
  count_all<<<NE / 256, 256, 0, stream>>>(dst, batch, counts, bcnt);
  scanA<<<NN / 256, 256, 0, stream>>>(counts, rp, bsum);
  scanB<<<1, 512, 0, stream>>>(bsum);
  scanC<<<NN / 256, 256, 0, stream>>>(rp, bsum);
  scan_batch<<<1, 1024, 0, stream>>>(bcnt, bp);
  scatter<<<NE / 256, 256, 0, stream>>>(src, dst, ea, rp, fill, eperm, sp,
                                        dst_p, ea_p, use_eap);
  prep_w2<<<2, 1024, 0, stream>>>(w12, w22, w2f);

  nodePQ1<<<1024, 256, 0, stream>>>(x, w11, b11, Pbuf, Qbuf);
  if (use_eap)
    edge_mfma<true><<<NE / 256, 256, 0, stream>>>(Pbuf, Qbuf, ea_p, ea, eperm, sp,
                                                  dst_p, rp, w11 + 32 * 64, w2f, b12, h1);
  else
    edge_mfma<false><<<NE / 256, 256, 0, stream>>>(Pbuf, Qbuf, ea_p, ea, eperm, sp,
                                                   dst_p, rp, w11 + 32 * 64, w2f, b12, h1);

  nodePQ2<<<1024, 256, 0, stream>>>(h1, w21, b21, Pbuf, Qbuf);
  if (use_eap)
    edge_mfma<true><<<NE / 256, 256, 0, stream>>>(Pbuf, Qbuf, ea_p, ea, eperm, sp,
                                                  dst_p, rp, w21 + 128 * 64, w2f + 4096, b22, h2);
  else
    edge_mfma<false><<<NE / 256, 256, 0, stream>>>(Pbuf, Qbuf, ea_p, ea, eperm, sp,
                                                   dst_p, rp, w21 + 128 * 64, w2f + 4096, b22, h2);

  readout<<<NG, 256, 0, stream>>>(h2, bp, wr1, br1, wr2, br2, out);
}

// Round 7
// 1026.426 us; speedup vs baseline: 1.8223x; 1.8223x over previous
//
#include <hip/hip_runtime.h>
#include <stdint.h>

#define NN 131072
#define NE 2097152
#define NG 1024

typedef float f32x4 __attribute__((ext_vector_type(4)));
typedef short bf16x8 __attribute__((ext_vector_type(8)));

// monotone float<->uint encoding: f1 < f2  <=>  enc(f1) < enc(f2) (unsigned).
__device__ __forceinline__ unsigned enc_f32(float f) {
  unsigned b = __float_as_uint(f);
  return (b & 0x80000000u) ? ~b : (b | 0x80000000u);
}
__device__ __forceinline__ float dec_pos(unsigned u) {
  return __uint_as_float(u & 0x7fffffffu);
}
// pack the high16 (truncated bf16) of two fp32 into one dword: [u1.hi | u0.hi]
__device__ __forceinline__ unsigned pack_hi(unsigned u0, unsigned u1) {
  return __builtin_amdgcn_perm(u1, u0, 0x07060302u);
}

// ---------------- init ----------------
__global__ void init_ws(uint4* __restrict__ h1, uint4* __restrict__ h2,
                        int* __restrict__ counts, int* __restrict__ fill,
                        int* __restrict__ bcnt) {
  const int HN4 = NN * 64 / 4;
  uint4 v = make_uint4(0x80000000u, 0x80000000u, 0x80000000u, 0x80000000u);
  int stride = gridDim.x * blockDim.x;
  for (int t = blockIdx.x * blockDim.x + threadIdx.x; t < HN4; t += stride) {
    h1[t] = v;
    h2[t] = v;
  }
  for (int t = blockIdx.x * blockDim.x + threadIdx.x; t < NN; t += stride) {
    counts[t] = 0;
    fill[t] = 0;
  }
  for (int t = blockIdx.x * blockDim.x + threadIdx.x; t < NG; t += stride)
    bcnt[t] = 0;
}

// ---------------- CSR build ----------------
__global__ __launch_bounds__(256) void count_all(const int* __restrict__ dst,
                                                 const int* __restrict__ batch,
                                                 int* __restrict__ counts,
                                                 int* __restrict__ bcnt) {
  int e = blockIdx.x * 256 + threadIdx.x;
  atomicAdd(&counts[dst[e]], 1);
  if (e < NN) atomicAdd(&bcnt[batch[e]], 1);
}

__global__ __launch_bounds__(256) void scanA(const int* __restrict__ counts,
                                             int* __restrict__ rp,
                                             int* __restrict__ bsum) {
  __shared__ int sm[256];
  int t = threadIdx.x;
  int g = blockIdx.x * 256 + t;
  int v = counts[g];
  sm[t] = v;
  __syncthreads();
  for (int off = 1; off < 256; off <<= 1) {
    int a = (t >= off) ? sm[t - off] : 0;
    __syncthreads();
    sm[t] += a;
    __syncthreads();
  }
  rp[g] = sm[t] - v;
  if (t == 255) bsum[blockIdx.x] = sm[255];
}

__global__ __launch_bounds__(512) void scanB(int* __restrict__ bsum) {
  __shared__ int sm[512];
  int t = threadIdx.x;
  int v = bsum[t];
  sm[t] = v;
  __syncthreads();
  for (int off = 1; off < 512; off <<= 1) {
    int a = (t >= off) ? sm[t - off] : 0;
    __syncthreads();
    sm[t] += a;
    __syncthreads();
  }
  bsum[t] = sm[t] - v;
}

__global__ __launch_bounds__(256) void scanC(int* __restrict__ rp,
                                             const int* __restrict__ bsum) {
  int g = blockIdx.x * 256 + threadIdx.x;
  rp[g] += bsum[blockIdx.x];
  if (g == 0) rp[NN] = NE;
}

__global__ __launch_bounds__(1024) void scan_batch(const int* __restrict__ bcnt,
                                                   int* __restrict__ bp) {
  __shared__ int sm[1024];
  int t = threadIdx.x;
  int v = bcnt[t];
  sm[t] = v;
  __syncthreads();
  for (int off = 1; off < 1024; off <<= 1) {
    int a = (t >= off) ? sm[t - off] : 0;
    __syncthreads();
    sm[t] += a;
    __syncthreads();
  }
  bp[t] = sm[t] - v;
  if (t == 1023) bp[NG] = NN;
}

__global__ __launch_bounds__(256) void scatter(
    const int* __restrict__ src, const int* __restrict__ dst,
    const float* __restrict__ ea, const int* __restrict__ rp,
    int* __restrict__ fill, int* __restrict__ eperm, int* __restrict__ sp,
    int* __restrict__ dst_p, float* __restrict__ ea_p, int use_eap) {
  int e = blockIdx.x * 256 + threadIdx.x;
  int d = dst[e];
  int p = rp[d] + atomicAdd(&fill[d], 1);
  sp[p] = src[e];
  dst_p[p] = d;
  if (use_eap) {
    const float2* s2 = (const float2*)(ea + (size_t)e * 6);
    float2 a = s2[0], b = s2[1], c = s2[2];
    float2* d2 = (float2*)(ea_p + (size_t)p * 6);
    d2[0] = a; d2[1] = b; d2[2] = c;
  } else {
    eperm[p] = e;
  }
}

// ---------------- W2 -> bf16 hi/lo B-fragment pre-pack ----------------
// layout per conv: [dt(2: hi,lo)][kc(2)][nt(4)][lane(64)][4 dwords]
// B-frag for mfma_f32_16x16x32_bf16: lane l holds B[k][n] with n = nt*16+(l&15),
// k = kc*32 + (l>>4)*8 + j (j=0..7, 2 bf16/dword, low16 = even j).
__global__ __launch_bounds__(1024) void prep_w2(const float* __restrict__ w2a,
                                                const float* __restrict__ w2b,
                                                unsigned* __restrict__ w2f) {
  int tid = threadIdx.x;
  const float* w2 = blockIdx.x ? w2b : w2a;
  unsigned* outp = w2f + blockIdx.x * 4096;
  int dt = tid >> 9, kc = (tid >> 8) & 1, nt = (tid >> 6) & 3, lane = tid & 63;
  int kbase = kc * 32 + (lane >> 4) * 8;
  int n = nt * 16 + (lane & 15);
  unsigned dwords[4];
#pragma unroll
  for (int i = 0; i < 4; i++) {
    float w0 = w2[(kbase + 2 * i) * 64 + n];
    float w1 = w2[(kbase + 2 * i + 1) * 64 + n];
    unsigned u0 = __float_as_uint(w0), u1 = __float_as_uint(w1);
    if (dt == 0) {
      dwords[i] = pack_hi(u0, u1);
    } else {
      float l0 = w0 - __uint_as_float(u0 & 0xffff0000u);
      float l1 = w1 - __uint_as_float(u1 & 0xffff0000u);
      dwords[i] = pack_hi(__float_as_uint(l0), __float_as_uint(l1));
    }
  }
  *(uint4*)(outp + ((dt * 2 + kc) * 4 + nt) * 256 + lane * 4) =
      make_uint4(dwords[0], dwords[1], dwords[2], dwords[3]);
}

// ---------------- node-level GEMMs: P = H@Wd + b1, Q = H@Ws ----------------
__global__ __launch_bounds__(256, 4) void nodePQ1(
    const float* __restrict__ x, const float* __restrict__ w1,
    const float* __restrict__ b1, float* __restrict__ P, float* __restrict__ Q) {
  int half = blockIdx.x >> 9;
  int n = (blockIdx.x & 511) * 256 + threadIdx.x;
  const float* w = w1 + half * 16 * 64;
  float acc[64];
#pragma unroll
  for (int j = 0; j < 64; j++) acc[j] = half ? 0.0f : b1[j];
  const float4* x4 = (const float4*)(x + (size_t)n * 16);
#pragma unroll
  for (int kk = 0; kk < 4; kk++) {
    float4 v = x4[kk];
    const float* wr = w + (kk * 4) * 64;
#pragma unroll
    for (int j = 0; j < 64; j++) acc[j] = fmaf(v.x, wr[j], acc[j]);
#pragma unroll
    for (int j = 0; j < 64; j++) acc[j] = fmaf(v.y, wr[64 + j], acc[j]);
#pragma unroll
    for (int j = 0; j < 64; j++) acc[j] = fmaf(v.z, wr[128 + j], acc[j]);
#pragma unroll
    for (int j = 0; j < 64; j++) acc[j] = fmaf(v.w, wr[192 + j], acc[j]);
  }
  float4* o = (float4*)((half ? Q : P) + (size_t)n * 64);
#pragma unroll
  for (int j = 0; j < 16; j++)
    o[j] = make_float4(acc[4 * j], acc[4 * j + 1], acc[4 * j + 2], acc[4 * j + 3]);
}

__global__ __launch_bounds__(256, 4) void nodePQ2(
    const unsigned* __restrict__ h1, const float* __restrict__ w1,
    const float* __restrict__ b1, float* __restrict__ P, float* __restrict__ Q) {
  int half = blockIdx.x >> 9;
  int n = (blockIdx.x & 511) * 256 + threadIdx.x;
  const float* w = w1 + half * 64 * 64;
  float acc[64];
#pragma unroll
  for (int j = 0; j < 64; j++) acc[j] = half ? 0.0f : b1[j];
  const uint4* h4 = (const uint4*)(h1 + (size_t)n * 64);
#pragma unroll 4
  for (int kk = 0; kk < 16; kk++) {
    uint4 u = h4[kk];
    float v0 = dec_pos(u.x), v1 = dec_pos(u.y), v2 = dec_pos(u.z), v3 = dec_pos(u.w);
    const float* wr = w + (kk * 4) * 64;
#pragma unroll
    for (int j = 0; j < 64; j++) acc[j] = fmaf(v0, wr[j], acc[j]);
#pragma unroll
    for (int j = 0; j < 64; j++) acc[j] = fmaf(v1, wr[64 + j], acc[j]);
#pragma unroll
    for (int j = 0; j < 64; j++) acc[j] = fmaf(v2, wr[128 + j], acc[j]);
#pragma unroll
    for (int j = 0; j < 64; j++) acc[j] = fmaf(v3, wr[192 + j], acc[j]);
  }
  float4* o = (float4*)((half ? Q : P) + (size_t)n * 64);
#pragma unroll
  for (int j = 0; j < 16; j++)
    o[j] = make_float4(acc[4 * j], acc[4 * j + 1], acc[4 * j + 2], acc[4 * j + 3]);
}

// ---------------- edge kernel: MFMA layer-2, wave = 64 CSR slots ----------------
// h(64 edges x 64 hidden) built on VALU in K-chunks of 32, split to bf16 hi/lo
// in a per-wave LDS tile; out = h @ W2 via mfma 16x16x32 with 3-term split
// (hi*hi + hi*lo + lo*hi); bias folded into acc init; epilogue = C dump to
// [ch][edge] LDS + serial uniform segmented max.
// NOTE: epilogue half-loop MUST be fully unrolled -- a runtime index into
// acc[][] demotes the accumulator to scratch (round-6 bug: 2 GB scratch).
template <bool EAP>
__global__ __launch_bounds__(256, 3) void edge_mfma(
    const float* __restrict__ P, const float* __restrict__ Q,
    const float* __restrict__ ea_p, const float* __restrict__ ea,
    const int* __restrict__ eperm, const int* __restrict__ sp,
    const int* __restrict__ dst_p, const int* __restrict__ rp,
    const float* __restrict__ w1c, const unsigned* __restrict__ w2f,
    const float* __restrict__ b2, unsigned* __restrict__ hout) {
  __shared__ __align__(16) unsigned lds[4][2176];  // per-wave 8.5 KB tile
  __shared__ int dar[4][64];

  int tid = threadIdx.x, wv = tid >> 6, lane = tid & 63;
  int lc = lane & 15, lg = lane >> 4;
  int g = blockIdx.x * 256 + tid;  // CSR slot; lane = slot within wave-tile
  int d = dst_p[g], s = sp[g];
  int seg_lo = rp[d], seg_hi = rp[d + 1];
  int wavebase = g - lane;
  bool whole = (seg_lo >= wavebase) && (seg_hi <= wavebase + 64);
  dar[wv][lane] = d | (whole ? (int)0x80000000 : 0);

  float2 ev[3];
  if (EAP) {
    const float2* q = (const float2*)(ea_p + (size_t)g * 6);
    ev[0] = q[0]; ev[1] = q[1]; ev[2] = q[2];
  } else {
    int e = eperm[g];
    const float2* q = (const float2*)(ea + (size_t)e * 6);
    ev[0] = q[0]; ev[1] = q[1]; ev[2] = q[2];
  }

  // acc init = bias (C/D layout: lane holds ch = nt*16+lc, rows = edges)
  f32x4 acc[4][4];
#pragma unroll
  for (int nt = 0; nt < 4; nt++) {
    float bv = b2[nt * 16 + lc];
#pragma unroll
    for (int mt = 0; mt < 4; mt++) acc[mt][nt] = (f32x4){bv, bv, bv, bv};
  }

  unsigned* hi_t = lds[wv];         // 64 rows x 16 dwords, block-XOR swizzled
  unsigned* lo_t = lds[wv] + 1024;
  int kw = (lane >> 1) & 3;  // write swizzle key (row = lane)
  int ka = (lc >> 1) & 3;    // A-frag read swizzle key (row = mt*16+lc)

#pragma unroll 1
  for (int kc = 0; kc < 2; ++kc) {
    float hj[32];
    {
      const float4* Pd = (const float4*)(P + (size_t)d * 64 + kc * 32);
      const float4* Qs = (const float4*)(Q + (size_t)s * 64 + kc * 32);
#pragma unroll
      for (int i = 0; i < 8; i++) {
        float4 a = Pd[i];
        float4 b = Qs[i];
        hj[4 * i] = a.x + b.x;
        hj[4 * i + 1] = a.y + b.y;
        hj[4 * i + 2] = a.z + b.z;
        hj[4 * i + 3] = a.w + b.w;
      }
#pragma unroll
      for (int t = 0; t < 3; t++) {
        const float* wr = w1c + (2 * t) * 64 + kc * 32;
#pragma unroll
        for (int j = 0; j < 32; j++) hj[j] = fmaf(ev[t].x, wr[j], hj[j]);
#pragma unroll
        for (int j = 0; j < 32; j++) hj[j] = fmaf(ev[t].y, wr[64 + j], hj[j]);
      }
#pragma unroll
      for (int j = 0; j < 32; j++) hj[j] = fmaxf(hj[j], 0.0f);
    }

    if (kc) asm volatile("s_waitcnt lgkmcnt(0)" ::: "memory");  // WAR vs kc=0 reads
#pragma unroll
    for (int q = 0; q < 4; q++) {  // 4-dword blocks, truncation hi/lo split
      unsigned hd[4], ld_[4];
#pragma unroll
      for (int i = 0; i < 4; i++) {
        float h0 = hj[q * 8 + 2 * i], h1 = hj[q * 8 + 2 * i + 1];
        unsigned u0 = __float_as_uint(h0), u1 = __float_as_uint(h1);
        hd[i] = pack_hi(u0, u1);
        float l0 = h0 - __uint_as_float(u0 & 0xffff0000u);
        float l1 = h1 - __uint_as_float(u1 & 0xffff0000u);
        ld_[i] = pack_hi(__float_as_uint(l0), __float_as_uint(l1));
      }
      int a = lane * 16 + 4 * (q ^ kw);
      *(uint4*)(hi_t + a) = make_uint4(hd[0], hd[1], hd[2], hd[3]);
      *(uint4*)(lo_t + a) = make_uint4(ld_[0], ld_[1], ld_[2], ld_[3]);
    }
    asm volatile("s_waitcnt lgkmcnt(0)" ::: "memory");  // writes visible to frag reads

    bf16x8 ah[4], al[4];
#pragma unroll
    for (int mt = 0; mt < 4; mt++) {
      int a = (mt * 16 + lc) * 16 + 4 * (lg ^ ka);
      ah[mt] = *(bf16x8*)(hi_t + a);
      al[mt] = *(bf16x8*)(lo_t + a);
    }
#pragma unroll
    for (int nt = 0; nt < 4; nt++) {
      bf16x8 bh = *(const bf16x8*)(w2f + ((0 + kc) * 4 + nt) * 256 + lane * 4);
      bf16x8 bl = *(const bf16x8*)(w2f + ((2 + kc) * 4 + nt) * 256 + lane * 4);
#pragma unroll
      for (int mt = 0; mt < 4; mt++) {
        acc[mt][nt] = __builtin_amdgcn_mfma_f32_16x16x32_bf16(ah[mt], bh, acc[mt][nt], 0, 0, 0);
        acc[mt][nt] = __builtin_amdgcn_mfma_f32_16x16x32_bf16(ah[mt], bl, acc[mt][nt], 0, 0, 0);
        acc[mt][nt] = __builtin_amdgcn_mfma_f32_16x16x32_bf16(al[mt], bh, acc[mt][nt], 0, 0, 0);
      }
    }
  }

  // ---- epilogue: per 32-ch half, dump C as [ch][edge] (pad 68, XOR-swizzled
  // edge index for conflict-free serial reads), then uniform segmented max.
  // FULLY UNROLLED so acc indices stay compile-time (registers). ----
  float* ct = (float*)lds[wv];  // 32 x 68 = 2176 dwords, aliases h tiles
  int kx = 4 * ((lane >> 3) & 3);  // scan-read XOR key (lane = channel row)
#pragma unroll
  for (int half = 0; half < 2; ++half) {
    asm volatile("s_waitcnt lgkmcnt(0)" ::: "memory");  // prior reads done
#pragma unroll
    for (int nt2 = 0; nt2 < 2; nt2++) {
      int chl = nt2 * 16 + lc;
      int kc2 = 4 * ((chl >> 3) & 3);
#pragma unroll
      for (int mt = 0; mt < 4; mt++) {
        int cb = (mt * 16 + 4 * lg) ^ kc2;
        *(f32x4*)(ct + chl * 68 + cb) = acc[mt][half * 2 + nt2];
      }
    }
    asm volatile("s_waitcnt lgkmcnt(0)" ::: "memory");  // C visible to scan
    if (lane < 32) {
      float mx = 0.0f;
      int cur = dar[wv][0];
      int base = lane * 68;
#pragma unroll 8
      for (int e = 0; e < 64; ++e) {
        float v = ct[base + (e ^ kx)];
        mx = fmaxf(mx, v);
        int nxt = (e < 63) ? dar[wv][e + 1] : 0x7fffffff;
        if (cur != nxt) {  // uniform: segment boundary -> flush
          unsigned* addr = hout + (size_t)(cur & 0x7fffffff) * 64 + half * 32 + lane;
          unsigned encv = enc_f32(mx);
          if (cur < 0) *addr = encv;   // whole-in-wave: plain store
          else atomicMax(addr, encv);  // crosses wave boundary
          mx = 0.0f;
        }
        cur = nxt;
      }
    }
  }
}

// ---------------- fused mean-pool + readout: 4-wave block per graph ----------------
__global__ __launch_bounds__(256) void readout(
    const unsigned* __restrict__ h2, const int* __restrict__ bp,
    const float* __restrict__ wr1, const float* __restrict__ br1,
    const float* __restrict__ wr2, const float* __restrict__ br2,
    float* __restrict__ out) {
  int g = blockIdx.x;
  int tid = threadIdx.x;
  int wv = tid >> 6, lane = tid & 63;
  int lo = bp[g], hi = bp[g + 1];
  float s = 0.0f;
  for (int n = lo + wv; n < hi; n += 4) s += dec_pos(h2[(size_t)n * 64 + lane]);
  __shared__ float part[4][64];
  __shared__ float p[64], t[64];
  part[wv][lane] = s;
  __syncthreads();
  if (tid < 64) {
    float c = fmaxf((float)(hi - lo), 1.0f);
    p[tid] = (part[0][tid] + part[1][tid] + part[2][tid] + part[3][tid]) / c;
  }
  __syncthreads();
  if (tid < 64) {
    float a = br1[tid];
#pragma unroll 8
    for (int k = 0; k < 64; k++) a = fmaf(p[k], wr1[k * 64 + tid], a);
    t[tid] = fmaxf(a, 0.0f);
  }
  __syncthreads();
  if (tid < 64) {
    float z0 = br2[tid], z1 = br2[64 + tid];
#pragma unroll 8
    for (int k = 0; k < 64; k++) {
      float tk = t[k];
      z0 = fmaf(tk, wr2[k * 128 + tid], z0);
      z1 = fmaf(tk, wr2[k * 128 + 64 + tid], z1);
    }
    out[(size_t)g * 128 + tid] = z0;
    out[(size_t)g * 128 + 64 + tid] = z1;
  }
}

// ---------------- launch ----------------
extern "C" void kernel_launch(void* const* d_in, const int* in_sizes, int n_in,
                              void* d_out, int out_size, void* d_ws, size_t ws_size,
                              hipStream_t stream) {
  const float* x     = (const float*)d_in[0];
  const float* ea    = (const float*)d_in[1];
  const int*   ei    = (const int*)d_in[2];
  const int*   batch = (const int*)d_in[3];
  const float* w11 = (const float*)d_in[4];
  const float* b11 = (const float*)d_in[5];
  const float* w12 = (const float*)d_in[6];
  const float* b12 = (const float*)d_in[7];
  const float* w21 = (const float*)d_in[8];
  const float* b21 = (const float*)d_in[9];
  const float* w22 = (const float*)d_in[10];
  const float* b22 = (const float*)d_in[11];
  const float* wr1 = (const float*)d_in[12];
  const float* br1 = (const float*)d_in[13];
  const float* wr2 = (const float*)d_in[14];
  const float* br2 = (const float*)d_in[15];
  float* out = (float*)d_out;

  const int* src = ei;
  const int* dst = ei + NE;

  char* ws = (char*)d_ws;
  size_t off = 0;
  auto alloc = [&](size_t bytes) {
    char* p = ws + off;
    off = (off + bytes + 255) & ~(size_t)255;
    return p;
  };
  unsigned* h1   = (unsigned*)alloc((size_t)NN * 64 * 4);
  unsigned* h2   = (unsigned*)alloc((size_t)NN * 64 * 4);
  float*    Pbuf = (float*)alloc((size_t)NN * 64 * 4);
  float*    Qbuf = (float*)alloc((size_t)NN * 64 * 4);
  int*   sp    = (int*)alloc((size_t)NE * 4);
  int*   eperm = (int*)alloc((size_t)NE * 4);
  int*   dst_p = (int*)alloc((size_t)NE * 4);
  int*   rp    = (int*)alloc((size_t)(NN + 1) * 4);
  int*   counts= (int*)alloc((size_t)NN * 4);
  int*   fill  = (int*)alloc((size_t)NN * 4);
  int*   bcnt  = (int*)alloc((size_t)NG * 4);
  int*   bp    = (int*)alloc((size_t)(NG + 1) * 4);
  int*   bsum  = (int*)alloc(512 * 4);
  unsigned* w2f = (unsigned*)alloc(2 * 4096 * 4);  // packed bf16 B-frags, 32 KB
  float* ea_p  = (float*)alloc((size_t)NE * 6 * 4);
  int use_eap = (off <= ws_size) ? 1 : 0;

  init_ws<<<1024, 256, 0, stream>>>((uint4*)h1, (uint4*)h2, counts, fill, bcnt);
  count_all<<<NE / 256, 256, 0, stream>>>(dst, batch, counts, bcnt);
  scanA<<<NN / 256, 256, 0, stream>>>(counts, rp, bsum);
  scanB<<<1, 512, 0, stream>>>(bsum);
  scanC<<<NN / 256, 256, 0, stream>>>(rp, bsum);
  scan_batch<<<1, 1024, 0, stream>>>(bcnt, bp);
  scatter<<<NE / 256, 256, 0, stream>>>(src, dst, ea, rp, fill, eperm, sp,
                                        dst_p, ea_p, use_eap);
  prep_w2<<<2, 1024, 0, stream>>>(w12, w22, w2f);

  nodePQ1<<<1024, 256, 0, stream>>>(x, w11, b11, Pbuf, Qbuf);
  if (use_eap)
    edge_mfma<true><<<NE / 256, 256, 0, stream>>>(Pbuf, Qbuf, ea_p, ea, eperm, sp,
                                                  dst_p, rp, w11 + 32 * 64, w2f, b12, h1);
  else
    edge_mfma<false><<<NE / 256, 256, 0, stream>>>(Pbuf, Qbuf, ea_p, ea, eperm, sp,
                                                   dst_p, rp, w11 + 32 * 64, w2f, b12, h1);

  nodePQ2<<<1024, 256, 0, stream>>>(h1, w21, b21, Pbuf, Qbuf);
  if (use_eap)
    edge_mfma<true><<<NE / 256, 256, 0, stream>>>(Pbuf, Qbuf, ea_p, ea, eperm, sp,
                                                  dst_p, rp, w21 + 128 * 64, w2f + 4096, b22, h2);
  else
    edge_mfma<false><<<NE / 256, 256, 0, stream>>>(Pbuf, Qbuf, ea_p, ea, eperm, sp,
                                                   dst_p, rp, w21 + 128 * 64, w2f + 4096, b22, h2);

  readout<<<NG, 256, 0, stream>>>(h2, bp, wr1, br1, wr2, br2, out);
}